// Round 17
// baseline (3967.506 us; speedup 1.0000x reference)
//
#include <hip/hip_runtime.h>
#include <hip/hip_bf16.h>

#define S_LEN 512
#define B_SZ  256
#define F_SZ  256
#define H_SZ  1024
#define BH    (B_SZ * H_SZ)
#define KEEP  0.5f

typedef float f32x4 __attribute__((ext_vector_type(4)));
typedef short s16x8 __attribute__((ext_vector_type(8)));
typedef int   i32x4 __attribute__((ext_vector_type(4)));

static __device__ __forceinline__ short f2bf(float f) {
    unsigned u = __builtin_bit_cast(unsigned, f);
    unsigned r = u + 0x7fffu + ((u >> 16) & 1u);   // RNE to bf16
    return (short)(r >> 16);
}

static __device__ __forceinline__ s16x8 pack8(f32x4 lo, f32x4 hi, float s) {
    s16x8 r;
#pragma unroll
    for (int i = 0; i < 4; ++i) { r[i] = f2bf(lo[i] * s); r[i + 4] = f2bf(hi[i] * s); }
    return r;
}

// packed converts (xi_gemm only — isolated kernel)
static __device__ __forceinline__ s16x8 pack8_pk(f32x4 lo, f32x4 hi) {
    int w0, w1, w2, w3;
    asm("v_cvt_pk_bf16_f32 %0, %1, %2" : "=v"(w0) : "v"(lo[0]), "v"(lo[1]));
    asm("v_cvt_pk_bf16_f32 %0, %1, %2" : "=v"(w1) : "v"(lo[2]), "v"(lo[3]));
    asm("v_cvt_pk_bf16_f32 %0, %1, %2" : "=v"(w2) : "v"(hi[0]), "v"(hi[1]));
    asm("v_cvt_pk_bf16_f32 %0, %1, %2" : "=v"(w3) : "v"(hi[2]), "v"(hi[3]));
    i32x4 r = { w0, w1, w2, w3 };
    return __builtin_bit_cast(s16x8, r);
}

static __device__ __forceinline__ long pack4_pk(f32x4 a) {
    int lo, hi;
    asm("v_cvt_pk_bf16_f32 %0, %1, %2" : "=v"(lo) : "v"(a[0]), "v"(a[1]));
    asm("v_cvt_pk_bf16_f32 %0, %1, %2" : "=v"(hi) : "v"(a[2]), "v"(a[3]));
    return (long)(((unsigned long)(unsigned)hi << 32) | (unsigned)lo);
}

static __device__ __forceinline__ f32x4 unpack4(long v) {
    unsigned lo = (unsigned)v, hi = (unsigned)((unsigned long)v >> 32);
    f32x4 r;
    r[0] = __builtin_bit_cast(float, lo << 16);
    r[1] = __builtin_bit_cast(float, lo & 0xffff0000u);
    r[2] = __builtin_bit_cast(float, hi << 16);
    r[3] = __builtin_bit_cast(float, hi & 0xffff0000u);
    return r;
}

static __device__ __forceinline__ float fast_tanh(float v) {
    float e = __expf(2.0f * v);
    return (e - 1.0f) / (e + 1.0f);
}

#define SYS_LD(p)   __hip_atomic_load((p), __ATOMIC_RELAXED, __HIP_MEMORY_SCOPE_SYSTEM)
#define SYS_ST(p,v) __hip_atomic_store((p), (v), __ATOMIC_RELAXED, __HIP_MEMORY_SCOPE_SYSTEM)
#define AGT_LD(p)   __hip_atomic_load((p), __ATOMIC_RELAXED, __HIP_MEMORY_SCOPE_AGENT)

// Flag atomics (R14-proven): PURE -> no sc1 (XCD-local TCC); mixed -> sc0 sc1.
template<int PURE>
static __device__ __forceinline__ int rmw_flag(int* p, int v) {
    int r;
    if constexpr (PURE)
        asm volatile("global_atomic_add %0, %1, %2, off sc0\n\ts_waitcnt vmcnt(0)"
                     : "=v"(r) : "v"(p), "v"(v) : "memory");
    else
        asm volatile("global_atomic_add %0, %1, %2, off sc0 sc1\n\ts_waitcnt vmcnt(0)"
                     : "=v"(r) : "v"(p), "v"(v) : "memory");
    return r;
}

template<int PURE>
static __device__ __forceinline__ void sig_flag(int* p) {
    int one = 1;
    if constexpr (PURE)
        asm volatile("global_atomic_add %0, %1, off" :: "v"(p), "v"(one) : "memory");
    else
        asm volatile("global_atomic_add %0, %1, off sc1" :: "v"(p), "v"(one) : "memory");
}

template<int PURE>
static __device__ __forceinline__ void sth(short* p, short v) {
    int vi = v;
    if constexpr (PURE)
        asm volatile("global_store_short %0, %1, off" :: "v"(p), "v"(vi) : "memory");
    else
        asm volatile("global_store_short %0, %1, off sc0 sc1" :: "v"(p), "v"(vi) : "memory");
}

#define MFMA(A, B, C) __builtin_amdgcn_mfma_f32_16x16x32_bf16((A), (B), (C), 0, 0, 0)

// ---------------- R14-proven coarse step loop (non-XI fallback) ----------------
template<int PURE>
static __device__ __forceinline__ void step_loop(
    const float* __restrict__ x, const float* __restrict__ h0,
    float* __restrict__ out, short* __restrict__ hbuf, int* __restrict__ flags,
    char* h_lds, const s16x8 (&wh)[32], const s16x8 (&wif)[8], float bj,
    int g, int b0, int role, int j, int wIdx, int wave, int lane, int tid, int dmask)
{
    const int ln = lane & 15;
    const int lk = lane >> 4;
    const int arow = b0 + ln;
    const int crow = b0 + lk * 4;
    const int xr = (ln & 7) << 4;
    const int rbase = ln * 2048 + lk * 16;
    int* const inbox  = flags + role * 64;
    int* const fanout = flags + ((g * 16 + lane) * 64 + wIdx);

#pragma unroll 1
    for (int s = 0; s < S_LEN; ++s) {
        f32x4 acc[4];
        acc[0] = f32x4{ bj, bj, bj, bj };
        acc[1] = f32x4{ 0.f, 0.f, 0.f, 0.f };
        acc[2] = f32x4{ 0.f, 0.f, 0.f, 0.f };
        acc[3] = f32x4{ 0.f, 0.f, 0.f, 0.f };

        const float* xp = x + ((size_t)s * B_SZ + arow) * F_SZ + lk * 8;
#pragma unroll
        for (int kf = 0; kf < 8; ++kf) {
            s16x8 a = pack8(*(const f32x4*)(xp + kf * 32),
                            *(const f32x4*)(xp + kf * 32 + 4), 1.0f);
            acc[kf & 1] = MFMA(a, wif[kf], acc[kf & 1]);
        }

        if (s > 0) {
            if (wave == 0) {
                int it = 0;
                for (;;) {
                    int v = rmw_flag<PURE>(inbox + lane, 0);
                    if (__all(v >= s)) break;
                    if (++it > (1 << 14)) break;
                    __builtin_amdgcn_s_sleep(1);
                }
            }
            __syncthreads();

            const char* slice = (const char*)(hbuf + (size_t)((s - 1) & dmask) * BH
                                              + (size_t)b0 * H_SZ);
            long o[16];
#pragma unroll
            for (int r = 0; r < 16; ++r) {
                const long* p = (const long*)(slice + r * 2048) + tid;
                o[r] = PURE ? AGT_LD(p) : SYS_LD(p);
            }
#pragma unroll
            for (int r = 0; r < 16; ++r)
                *(long*)(h_lds + ((r * 2048 + tid * 8) ^ ((r & 7) << 4))) = o[r];
            __syncthreads();

#pragma unroll
            for (int ks = 0; ks < 32; ++ks) {
                s16x8 a = *(const s16x8*)(h_lds + ((rbase + ks * 64) ^ xr));
                acc[ks & 3] = MFMA(a, wh[ks], acc[ks & 3]);
            }
        } else {
#pragma unroll
            for (int ks = 0; ks < 32; ++ks) {
                const float* p = h0 + ks * 32 + lk * 8;
                s16x8 a = pack8(*(const f32x4*)p, *(const f32x4*)(p + 4), KEEP);
                acc[ks & 3] = MFMA(a, wh[ks], acc[ks & 3]);
            }
        }

        f32x4 r4 = (acc[0] + acc[1]) + (acc[2] + acc[3]);

        if (s < S_LEN - 1) {
            short* op = hbuf + (size_t)(s & dmask) * BH;
#pragma unroll
            for (int r = 0; r < 4; ++r)
                sth<PURE>(op + (crow + r) * H_SZ + j, f2bf(KEEP * fast_tanh(r4[r])));
            asm volatile("s_waitcnt vmcnt(0)" ::: "memory");
            if (lane < 16) sig_flag<PURE>(fanout);
        } else {
#pragma unroll
            for (int r = 0; r < 4; ++r)
                out[(crow + r) * H_SZ + j] = fast_tanh(r4[r]);
        }
    }
}

// ---------------- wave-specialized paths (XI; both purities) ----------------
// Compute waves 0-3: R14-identical roles; consume via LDS flags only (no L2
// atomics, no __syncthreads in the hot loop). Static tile order -> all wh/acc
// indices compile-time (rule #20).
template<int PURE>
static __device__ __forceinline__ void spec_compute(
    const float* __restrict__ h0, float* __restrict__ out,
    short* __restrict__ hbuf, int* __restrict__ flags,
    const char* __restrict__ xi_lane, char* h_lds,
    volatile int* lflag, volatile int* ldone, const s16x8 (&wh)[32],
    int g, int b0, int j, int wIdx, int cw, int lane, int dmask)
{
    const int ln = lane & 15;
    const int lk = lane >> 4;
    const int crow = b0 + lk * 4;
    const int xr = (ln & 7) << 4;
    const int rbase = ln * 2048 + lk * 16;
    int* const fanout = flags + ((g * 16 + lane) * 64 + wIdx);

    long xv = *(const long*)xi_lane;   // step-0 xi

#pragma unroll 1
    for (int s = 0; s < S_LEN; ++s) {
        f32x4 acc[4];
        acc[0] = unpack4(xv);
        acc[1] = f32x4{ 0.f, 0.f, 0.f, 0.f };
        acc[2] = f32x4{ 0.f, 0.f, 0.f, 0.f };
        acc[3] = f32x4{ 0.f, 0.f, 0.f, 0.f };

        if (s > 0) {
            const char* lbuf = h_lds + (s & 1) * 32768;
            volatile int* lf = lflag + (s & 1) * 16;
#pragma unroll
            for (int tile = 0; tile < 16; ++tile) {        // tile is STATIC
                int it = 0;
                while (lf[tile] < s && ++it < (1 << 16)) { } // LDS broadcast spin
                __builtin_amdgcn_sched_barrier(0);          // reads stay below spin
#pragma unroll
                for (int half = 0; half < 2; ++half) {
                    const int ks = tile * 2 + half;         // STATIC wh/acc idx
                    s16x8 a = *(const s16x8*)(lbuf + ((rbase + ks * 64) ^ xr));
                    acc[ks & 3] = MFMA(a, wh[ks], acc[ks & 3]);
                }
            }
            __threadfence_block();            // drain reads before release
            if (lane == 0) ldone[cw] = s;     // stager may reuse this buffer
        } else {
            // step 0: h0 broadcast across batch (same fragment for all rows)
#pragma unroll
            for (int ks = 0; ks < 32; ++ks) {
                const float* p = h0 + ks * 32 + lk * 8;
                s16x8 a = pack8(*(const f32x4*)p, *(const f32x4*)(p + 4), KEEP);
                acc[ks & 3] = MFMA(a, wh[ks], acc[ks & 3]);
            }
        }

        f32x4 r4 = (acc[0] + acc[1]) + (acc[2] + acc[3]);

        // producer tail — byte-identical to R14
        if (s < S_LEN - 1) {
            short* op = hbuf + (size_t)(s & dmask) * BH;
#pragma unroll
            for (int r = 0; r < 4; ++r)
                sth<PURE>(op + (crow + r) * H_SZ + j, f2bf(KEEP * fast_tanh(r4[r])));
            asm volatile("s_waitcnt vmcnt(0)" ::: "memory");
            if (lane < 16) sig_flag<PURE>(fanout);
            xv = *(const long*)(xi_lane + (size_t)(s + 1) * (256u * 4 * 64 * 8));
        } else {
#pragma unroll
            for (int r = 0; r < 4; ++r)
                out[(crow + r) * H_SZ + j] = fast_tanh(r4[r]);
        }
    }
}

// Stager waves 4-7: poll own 4 producer WGs' inbox slots (L2 atomics OFF the
// compute path), stage 2KB tiles into double-buffered LDS, announce via
// monotonic LDS flags. Buffer reuse guarded by ldone (no cycle: compute sets
// ldone after consuming; never waits on this stager's CURRENT work).
template<int PURE>
static __device__ __forceinline__ void spec_stager(
    short* __restrict__ hbuf, int* __restrict__ flags, char* h_lds,
    volatile int* lflag, volatile int* ldone,
    int b0, int role, int sw, int lane, int dmask)
{
    int* const inbox = flags + role * 64;
    const int srow = lane & 15;          // row within the 16-row slice
    const int ub   = (lane >> 4) * 4;    // first 8B unit (4 consecutive per lane)
    const int xw   = (srow & 7) << 4;

#pragma unroll 1
    for (int s = 1; s < S_LEN; ++s) {
        if (s >= 3) {   // buf[s&1] last read at step s-2: wait for consumption
            int it = 0;
            for (;;) {
                int v = (lane < 4) ? ldone[lane] : s;
                if (__all(v >= s - 2)) break;
                if (++it > (1 << 16)) break;     // watchdog: fail-visible
            }
        }
        const char* slice = (const char*)(hbuf + (size_t)((s - 1) & dmask) * BH
                                          + (size_t)b0 * H_SZ);
        char* lbuf = lflag ? (h_lds + (s & 1) * 32768) : h_lds;
        volatile int* lf = lflag + (s & 1) * 16;

#pragma unroll
        for (int i = 0; i < 4; ++i) {
            const int tp = sw + i * 4;           // tile index (addresses only)
            int* sp = inbox + tp * 4 + (lane & 3);
            int it = 0;
            for (;;) {
                int v = (lane < 4) ? rmw_flag<PURE>(sp, 0) : s;
                if (__all(v >= s)) break;
                if (++it > (1 << 14)) break;     // watchdog: fail-visible
                __builtin_amdgcn_s_sleep(1);
            }
            __builtin_amdgcn_sched_barrier(0);
            const char* gb = slice + srow * 2048 + tp * 128;
#pragma unroll
            for (int q = 0; q < 4; ++q) {
                const int u = ub + q;
                long v = PURE ? AGT_LD((const long*)(gb + u * 8))
                              : SYS_LD((const long*)(gb + u * 8));
                *(long*)(lbuf + ((srow * 2048 + tp * 128 + u * 8) ^ xw)) = v;
            }
            __threadfence_block();               // LDS data before flag
            if (lane == 0) lf[tp] = s;
        }
    }
}

// ---------- kernel A: xi = x@Wi^T + b (sync-free; coalesced output) ----------
__global__ __launch_bounds__(256, 1) void xi_gemm(
    const float* __restrict__ x, const float* __restrict__ Wi,
    const float* __restrict__ bias, char* __restrict__ xi)
{
    const int bid  = blockIdx.x;
    const int role = bid & 255;
    const int c    = bid >> 8;
    const int tid  = threadIdx.x;
    const int wave = tid >> 6;
    const int lane = tid & 63;
    const int ln   = lane & 15;
    const int lk   = lane >> 4;

    const int b0    = (role >> 4) * 16;
    const int jtile = (role & 15) * 64;

    s16x8 wia[4][8];
    float b4[4];
#pragma unroll
    for (int jt = 0; jt < 4; ++jt) {
        b4[jt] = bias[jtile + jt * 16 + ln];
#pragma unroll
        for (int kf = 0; kf < 8; ++kf) {
            const float* p = Wi + (size_t)(jtile + jt * 16 + ln) * F_SZ
                           + kf * 32 + lk * 8;
            wia[jt][kf] = pack8_pk(*(const f32x4*)p, *(const f32x4*)(p + 4));
        }
    }

#pragma unroll 1
    for (int i = 0; i < 16; ++i) {
        const int s = c * 64 + wave + 4 * i;
        const float* xp = x + ((size_t)s * B_SZ + b0 + ln) * F_SZ + lk * 8;
        s16x8 af[8];
#pragma unroll
        for (int kf = 0; kf < 8; ++kf)
            af[kf] = pack8_pk(*(const f32x4*)(xp + kf * 32),
                              *(const f32x4*)(xp + kf * 32 + 4));
#pragma unroll
        for (int jt = 0; jt < 4; ++jt) {
            f32x4 a = { b4[jt], b4[jt], b4[jt], b4[jt] };
#pragma unroll
            for (int kf = 0; kf < 8; ++kf)
                a = MFMA(af[kf], wia[jt][kf], a);
            *(long*)(xi + ((((size_t)s * 256 + role) * 4 + jt) * 64 + lane) * 8)
                = pack4_pk(a);
        }
    }
}

// ---------- kernel B1: wave-specialized recurrence (XI path) ----------
__global__ __launch_bounds__(512, 1) void rnn_spec(
    const float* __restrict__ x, const float* __restrict__ Wi,
    const float* __restrict__ bias, const float* __restrict__ Wh,
    const float* __restrict__ h0, float* __restrict__ out,
    short* __restrict__ hbuf, int* __restrict__ roster, int* __restrict__ flags,
    const char* __restrict__ xi, int dmask)
{
    __shared__ char h_lds[2 * 32768 + 256];   // 2 buffers + lflag[32] + ldone[4]
    __shared__ int sh_pure;
    volatile int* lflag = (volatile int*)(h_lds + 65536);
    volatile int* ldone = (volatile int*)(h_lds + 65536 + 128);

    const int bid  = blockIdx.x;
    const int role = ((bid & 7) << 5) | (bid >> 3);   // same-XCD groups under RR lore
    const int g    = role >> 4;
    const int t    = role & 15;
    const int tid  = threadIdx.x;
    const int wave = tid >> 6;      // 0-3 compute, 4-7 stagers
    const int lane = tid & 63;
    const int ln   = lane & 15;
    const int lk   = lane >> 4;

    if (tid < 32) lflag[tid] = 0;
    if (tid < 4)  ldone[tid] = 0;

    int xcc;
    asm volatile("s_getreg_b32 %0, hwreg(HW_REG_XCC_ID)" : "=s"(xcc));
    xcc &= 7;
    if (tid == 0) SYS_ST(&roster[role], xcc + 1);
    if (tid < 16) {
        const int* rp = roster + g * 16 + tid;
        int v, it = 0;
        do { v = SYS_LD(rp); if (v) break; if (++it > (1 << 18)) break;
             __builtin_amdgcn_s_sleep(1); } while (1);
        int p = __all(v == __shfl(v, 0));
        if (tid == 0) sh_pure = p;
    }
    __syncthreads();   // covers lflag/ldone init + sh_pure
    const int pure = sh_pure;
    const int b0 = g * 16;

    if (wave < 4) {
        const int j = t * 64 + wave * 16 + ln;
        const int wIdx = t * 4 + wave;
        const char* xi_lane = xi + (((size_t)role * 4 + wave) * 64 + lane) * 8;
        s16x8 wh[32];
#pragma unroll
        for (int ks = 0; ks < 32; ++ks) {
            const float* p = Wh + (size_t)j * H_SZ + ks * 32 + lk * 8;
            wh[ks] = pack8(*(const f32x4*)p, *(const f32x4*)(p + 4), 1.0f);
        }
        if (pure)
            spec_compute<1>(h0, out, hbuf, flags, xi_lane, h_lds, lflag, ldone,
                            wh, g, b0, j, wIdx, wave, lane, dmask);
        else
            spec_compute<0>(h0, out, hbuf, flags, xi_lane, h_lds, lflag, ldone,
                            wh, g, b0, j, wIdx, wave, lane, dmask);
    } else {
        const int sw = wave - 4;
        if (pure)
            spec_stager<1>(hbuf, flags, h_lds, lflag, ldone, b0, role, sw, lane, dmask);
        else
            spec_stager<0>(hbuf, flags, h_lds, lflag, ldone, b0, role, sw, lane, dmask);
    }
}

// ---------- kernel B2: coarse recurrence (non-XI fallback, R14-proven) ----------
__global__ __launch_bounds__(256, 1) void rnn_coarse(
    const float* __restrict__ x, const float* __restrict__ Wi,
    const float* __restrict__ bias, const float* __restrict__ Wh,
    const float* __restrict__ h0, float* __restrict__ out,
    short* __restrict__ hbuf, int* __restrict__ roster, int* __restrict__ flags,
    int dmask)
{
    __shared__ char h_lds[32768];
    __shared__ int sh_pure;
    const int bid  = blockIdx.x;
    const int role = ((bid & 7) << 5) | (bid >> 3);
    const int g    = role >> 4;
    const int t    = role & 15;
    const int tid  = threadIdx.x;
    const int wave = tid >> 6;
    const int lane = tid & 63;
    const int ln   = lane & 15;
    const int lk   = lane >> 4;

    int xcc;
    asm volatile("s_getreg_b32 %0, hwreg(HW_REG_XCC_ID)" : "=s"(xcc));
    xcc &= 7;
    if (tid == 0) SYS_ST(&roster[role], xcc + 1);
    if (tid < 16) {
        const int* rp = roster + g * 16 + tid;
        int v, it = 0;
        do { v = SYS_LD(rp); if (v) break; if (++it > (1 << 18)) break;
             __builtin_amdgcn_s_sleep(1); } while (1);
        int p = __all(v == __shfl(v, 0));
        if (tid == 0) sh_pure = p;
    }
    __syncthreads();
    const int pure = sh_pure;

    const int b0 = g * 16;
    const int j  = t * 64 + wave * 16 + ln;
    const int wIdx = t * 4 + wave;

    s16x8 wh[32];
#pragma unroll
    for (int ks = 0; ks < 32; ++ks) {
        const float* p = Wh + (size_t)j * H_SZ + ks * 32 + lk * 8;
        wh[ks] = pack8(*(const f32x4*)p, *(const f32x4*)(p + 4), 1.0f);
    }
    s16x8 wif[8];
#pragma unroll
    for (int kf = 0; kf < 8; ++kf) {
        const float* p = Wi + (size_t)j * F_SZ + kf * 32 + lk * 8;
        wif[kf] = pack8(*(const f32x4*)p, *(const f32x4*)(p + 4), 1.0f);
    }
    const float bj = bias[j];

    if (pure)
        step_loop<1>(x, h0, out, hbuf, flags, h_lds, wh, wif, bj,
                     g, b0, role, j, wIdx, wave, lane, tid, dmask);
    else
        step_loop<0>(x, h0, out, hbuf, flags, h_lds, wh, wif, bj,
                     g, b0, role, j, wIdx, wave, lane, tid, dmask);
}

extern "C" void kernel_launch(void* const* d_in, const int* in_sizes, int n_in,
                              void* d_out, int out_size, void* d_ws, size_t ws_size,
                              hipStream_t stream) {
    const float* x  = (const float*)d_in[0];
    const float* Wi = (const float*)d_in[1];
    const float* bi = (const float*)d_in[2];
    const float* Wh = (const float*)d_in[3];
    const float* h0 = (const float*)d_in[4];
    float* out = (float*)d_out;

    int*   roster = (int*)d_ws;                          // 256 ints @ 0
    int*   flags  = (int*)((char*)d_ws + (4 << 10));     // 256 inboxes x 64 = 64KB
    short* hbuf   = (short*)((char*)d_ws + (128 << 10)); // depth x 512 KB bf16
    char*  xi     = (char*)d_ws + (128 << 10) + 4 * (size_t)BH * 2;

    const size_t need4   = (128u << 10) + 4 * (size_t)BH * 2;          // ~2.1 MB
    const size_t need_xi = need4 + (size_t)S_LEN * 256 * 4 * 64 * 8;   // ~270.7 MB

    const int dmask = (ws_size >= need4) ? 3 : 1;

    // roster + inboxes MUST be zero every call (graph replays don't re-poison)
    (void)hipMemsetAsync(d_ws, 0, (68 << 10), stream);

    if (ws_size >= need_xi) {
        xi_gemm<<<dim3(2048), dim3(256), 0, stream>>>(x, Wi, bi, xi);
        rnn_spec<<<dim3(256), dim3(512), 0, stream>>>(
            x, Wi, bi, Wh, h0, out, hbuf, roster, flags, xi, 3);
    } else {
        rnn_coarse<<<dim3(256), dim3(256), 0, stream>>>(
            x, Wi, bi, Wh, h0, out, hbuf, roster, flags, dmask);
    }
}

// Round 18
// 2061.045 us; speedup vs baseline: 1.9250x; 1.9250x over previous
//
#include <hip/hip_runtime.h>
#include <hip/hip_bf16.h>

#define S_LEN 512
#define B_SZ  256
#define F_SZ  256
#define H_SZ  1024
#define BH    (B_SZ * H_SZ)
#define KEEP  0.5f

typedef float f32x4 __attribute__((ext_vector_type(4)));
typedef short s16x8 __attribute__((ext_vector_type(8)));
typedef int   i32x4 __attribute__((ext_vector_type(4)));

static __device__ __forceinline__ short f2bf(float f) {
    unsigned u = __builtin_bit_cast(unsigned, f);
    unsigned r = u + 0x7fffu + ((u >> 16) & 1u);   // RNE to bf16
    return (short)(r >> 16);
}

static __device__ __forceinline__ s16x8 pack8(f32x4 lo, f32x4 hi, float s) {
    s16x8 r;
#pragma unroll
    for (int i = 0; i < 4; ++i) { r[i] = f2bf(lo[i] * s); r[i + 4] = f2bf(hi[i] * s); }
    return r;
}

// packed converts (xi_gemm only — isolated kernel)
static __device__ __forceinline__ s16x8 pack8_pk(f32x4 lo, f32x4 hi) {
    int w0, w1, w2, w3;
    asm("v_cvt_pk_bf16_f32 %0, %1, %2" : "=v"(w0) : "v"(lo[0]), "v"(lo[1]));
    asm("v_cvt_pk_bf16_f32 %0, %1, %2" : "=v"(w1) : "v"(lo[2]), "v"(lo[3]));
    asm("v_cvt_pk_bf16_f32 %0, %1, %2" : "=v"(w2) : "v"(hi[0]), "v"(hi[1]));
    asm("v_cvt_pk_bf16_f32 %0, %1, %2" : "=v"(w3) : "v"(hi[2]), "v"(hi[3]));
    i32x4 r = { w0, w1, w2, w3 };
    return __builtin_bit_cast(s16x8, r);
}

static __device__ __forceinline__ long pack4_pk(f32x4 a) {
    int lo, hi;
    asm("v_cvt_pk_bf16_f32 %0, %1, %2" : "=v"(lo) : "v"(a[0]), "v"(a[1]));
    asm("v_cvt_pk_bf16_f32 %0, %1, %2" : "=v"(hi) : "v"(a[2]), "v"(a[3]));
    return (long)(((unsigned long)(unsigned)hi << 32) | (unsigned)lo);
}

static __device__ __forceinline__ f32x4 unpack4(long v) {
    unsigned lo = (unsigned)v, hi = (unsigned)((unsigned long)v >> 32);
    f32x4 r;
    r[0] = __builtin_bit_cast(float, lo << 16);
    r[1] = __builtin_bit_cast(float, lo & 0xffff0000u);
    r[2] = __builtin_bit_cast(float, hi << 16);
    r[3] = __builtin_bit_cast(float, hi & 0xffff0000u);
    return r;
}

static __device__ __forceinline__ float fast_tanh(float v) {
    float e = __expf(2.0f * v);
    return (e - 1.0f) / (e + 1.0f);
}

#define SYS_LD(p)   __hip_atomic_load((p), __ATOMIC_RELAXED, __HIP_MEMORY_SCOPE_SYSTEM)
#define SYS_ST(p,v) __hip_atomic_store((p), (v), __ATOMIC_RELAXED, __HIP_MEMORY_SCOPE_SYSTEM)
#define AGT_LD(p)   __hip_atomic_load((p), __ATOMIC_RELAXED, __HIP_MEMORY_SCOPE_AGENT)

// Flag atomics (R14-proven): PURE -> no sc1 (XCD-local TCC); mixed -> sc0 sc1.
template<int PURE>
static __device__ __forceinline__ int rmw_flag(int* p, int v) {
    int r;
    if constexpr (PURE)
        asm volatile("global_atomic_add %0, %1, %2, off sc0\n\ts_waitcnt vmcnt(0)"
                     : "=v"(r) : "v"(p), "v"(v) : "memory");
    else
        asm volatile("global_atomic_add %0, %1, %2, off sc0 sc1\n\ts_waitcnt vmcnt(0)"
                     : "=v"(r) : "v"(p), "v"(v) : "memory");
    return r;
}

template<int PURE>
static __device__ __forceinline__ void sig_flag(int* p) {
    int one = 1;
    if constexpr (PURE)
        asm volatile("global_atomic_add %0, %1, off" :: "v"(p), "v"(one) : "memory");
    else
        asm volatile("global_atomic_add %0, %1, off sc1" :: "v"(p), "v"(one) : "memory");
}

template<int PURE>
static __device__ __forceinline__ void sth(short* p, short v) {
    int vi = v;
    if constexpr (PURE)
        asm volatile("global_store_short %0, %1, off" :: "v"(p), "v"(vi) : "memory");
    else
        asm volatile("global_store_short %0, %1, off sc0 sc1" :: "v"(p), "v"(vi) : "memory");
}

#define MFMA(A, B, C) __builtin_amdgcn_mfma_f32_16x16x32_bf16((A), (B), (C), 0, 0, 0)

// ---------- 512-thread recurrence (XI path): R14 chain, smaller topology ----------
// Group = 8 WGs x 512 thr (was 16 x 256): signal fan-out halves, polling WGs
// halve, 8 waves share each 32KB LDS stage (L2 stage traffic halves).
template<int PURE>
static __device__ __forceinline__ void step_loop512(
    const float* __restrict__ h0, float* __restrict__ out,
    short* __restrict__ hbuf, int* __restrict__ flags,
    const char* __restrict__ xi_lane, char* h_lds, const s16x8 (&wh)[32],
    int g, int b0, int role, int j, int wIdx, int wave, int lane, int tid, int dmask)
{
    const int ln = lane & 15;
    const int lk = lane >> 4;
    const int crow = b0 + lk * 4;
    const int xr = (ln & 7) << 4;                 // read-side LDS swizzle
    const int rbase = ln * 2048 + lk * 16;        // A-frag base byte in h_lds
    const int u  = tid & 255;                     // staging 8B-unit within row
    const int rh = tid >> 8;                      // staging row parity
    int* const inbox = flags + role * 64;         // my WG's 64 counters

    long xv = *(const long*)xi_lane;              // s=0 prefetch

#pragma unroll 1
    for (int s = 0; s < S_LEN; ++s) {
        f32x4 acc[4];
        acc[0] = unpack4(xv);
        acc[1] = f32x4{ 0.f, 0.f, 0.f, 0.f };
        acc[2] = f32x4{ 0.f, 0.f, 0.f, 0.f };
        acc[3] = f32x4{ 0.f, 0.f, 0.f, 0.f };

        if (s > 0) {
            // ---- wave0: atomic RMW poll on own inbox (R14-proven) ----
            if (wave == 0) {
                int it = 0;
                for (;;) {
                    int v = rmw_flag<PURE>(inbox + lane, 0);
                    if (__all(v >= s)) break;
                    if (++it > (1 << 14)) break;    // watchdog: fail-visible
                    __builtin_amdgcn_s_sleep(1);
                }
            }
            __syncthreads();   // release waves 1-7; orders poll before loads

            // ---- stage 32KB h slice -> LDS (8 x 8B per thread) ----
            const char* slice = (const char*)(hbuf + (size_t)((s - 1) & dmask) * BH
                                              + (size_t)b0 * H_SZ);
            long o[8];
#pragma unroll
            for (int r = 0; r < 8; ++r) {
                const long* p = (const long*)(slice + (rh + 2 * r) * 2048) + u;
                o[r] = PURE ? AGT_LD(p) : SYS_LD(p);
            }
#pragma unroll
            for (int r = 0; r < 8; ++r) {
                int row = rh + 2 * r;
                *(long*)(h_lds + ((row * 2048 + u * 8) ^ ((row & 7) << 4))) = o[r];
            }
            __syncthreads();

            // ---- 32 h-MFMAs from swizzled LDS, 4 independent chains ----
#pragma unroll
            for (int ks = 0; ks < 32; ++ks) {
                s16x8 a = *(const s16x8*)(h_lds + ((rbase + ks * 64) ^ xr));
                acc[ks & 3] = MFMA(a, wh[ks], acc[ks & 3]);
            }
        } else {
            // step 0: h0 broadcast across batch (same fragment for all rows)
#pragma unroll
            for (int ks = 0; ks < 32; ++ks) {
                const float* p = h0 + ks * 32 + lk * 8;
                s16x8 a = pack8(*(const f32x4*)p, *(const f32x4*)(p + 4), KEEP);
                acc[ks & 3] = MFMA(a, wh[ks], acc[ks & 3]);
            }
        }

        f32x4 r4 = (acc[0] + acc[1]) + (acc[2] + acc[3]);

        // C/D layout: col = lane&15 (=j), row = (lane>>4)*4 + r (=batch)
        if (s < S_LEN - 1) {
            short* op = hbuf + (size_t)(s & dmask) * BH;
#pragma unroll
            for (int r = 0; r < 4; ++r)
                sth<PURE>(op + (crow + r) * H_SZ + j, f2bf(KEEP * fast_tanh(r4[r])));
            asm volatile("s_waitcnt vmcnt(0)" ::: "memory");  // h at L2/L3 first
            if (lane < 8) sig_flag<PURE>(flags + ((g * 8 + lane) * 64 + wIdx));
            // prefetch next step's xi: HBM latency hides in the next wait
            xv = *(const long*)(xi_lane + (size_t)(s + 1) * (256u * 4 * 64 * 8));
        } else {
#pragma unroll
            for (int r = 0; r < 4; ++r)
                out[(crow + r) * H_SZ + j] = fast_tanh(r4[r]);
        }
    }
}

__global__ __launch_bounds__(512, 2) void rnn512(
    const float* __restrict__ Wh, const float* __restrict__ h0,
    float* __restrict__ out, short* __restrict__ hbuf,
    int* __restrict__ roster, int* __restrict__ flags,
    const char* __restrict__ xi, int dmask)
{
    __shared__ char h_lds[32768];
    __shared__ int sh_pure;
    const int bid  = blockIdx.x;                      // 0..127
    const int role = ((bid & 7) << 4) | (bid >> 3);   // same-XCD groups under RR lore
    const int g    = role >> 3;                       // batch-group 0..15
    const int t    = role & 7;                        // j-tile (128 cols) 0..7
    const int tid  = threadIdx.x;
    const int wave = tid >> 6;                        // 0..7
    const int lane = tid & 63;
    const int ln   = lane & 15;
    const int lk   = lane >> 4;

    int xcc;
    asm volatile("s_getreg_b32 %0, hwreg(HW_REG_XCC_ID)" : "=s"(xcc));
    xcc &= 7;
    if (tid == 0) SYS_ST(&roster[role], xcc + 1);     // publish my XCD (one-time)
    if (tid < 8) {                                    // verify group co-residency
        const int* rp = roster + g * 8 + tid;
        int v, it = 0;
        do { v = SYS_LD(rp); if (v) break; if (++it > (1 << 18)) break;
             __builtin_amdgcn_s_sleep(1); } while (1);
        int p = __all(v == __shfl(v, 0));
        if (tid == 0) sh_pure = p;
    }
    __syncthreads();
    const int pure = sh_pure;

    const int b0 = g * 16;
    const int j  = t * 128 + wave * 16 + ln;
    const int wIdx = t * 8 + wave;                    // producer wave id 0..63

    // consumer xi address in the (unchanged) producer-coalesced layout:
    // [s][role256=(g<<4)|(j>>6)][jt=(j>>4)&3][lane=(lk<<4)|ln] x 8B
    const char* xi_lane = xi
        + ((((size_t)((g << 4) | (j >> 6))) * 4 + ((j >> 4) & 3)) * 64
           + ((lk << 4) | ln)) * 8;

    s16x8 wh[32];
#pragma unroll
    for (int ks = 0; ks < 32; ++ks) {
        const float* p = Wh + (size_t)j * H_SZ + ks * 32 + lk * 8;
        wh[ks] = pack8(*(const f32x4*)p, *(const f32x4*)(p + 4), 1.0f);
    }

    if (pure)
        step_loop512<1>(h0, out, hbuf, flags, xi_lane, h_lds, wh,
                        g, b0, role, j, wIdx, wave, lane, tid, dmask);
    else
        step_loop512<0>(h0, out, hbuf, flags, xi_lane, h_lds, wh,
                        g, b0, role, j, wIdx, wave, lane, tid, dmask);
}

// ---------------- R14-proven coarse fallback (non-XI, 256 thr) ----------------
template<int PURE>
static __device__ __forceinline__ void step_loop(
    const float* __restrict__ x, const float* __restrict__ h0,
    float* __restrict__ out, short* __restrict__ hbuf, int* __restrict__ flags,
    char* h_lds, const s16x8 (&wh)[32], const s16x8 (&wif)[8], float bj,
    int g, int b0, int role, int j, int wIdx, int wave, int lane, int tid, int dmask)
{
    const int ln = lane & 15;
    const int lk = lane >> 4;
    const int arow = b0 + ln;
    const int crow = b0 + lk * 4;
    const int xr = (ln & 7) << 4;
    const int rbase = ln * 2048 + lk * 16;
    int* const inbox  = flags + role * 64;
    int* const fanout = flags + ((g * 16 + lane) * 64 + wIdx);

#pragma unroll 1
    for (int s = 0; s < S_LEN; ++s) {
        f32x4 acc[4];
        acc[0] = f32x4{ bj, bj, bj, bj };
        acc[1] = f32x4{ 0.f, 0.f, 0.f, 0.f };
        acc[2] = f32x4{ 0.f, 0.f, 0.f, 0.f };
        acc[3] = f32x4{ 0.f, 0.f, 0.f, 0.f };

        const float* xp = x + ((size_t)s * B_SZ + arow) * F_SZ + lk * 8;
#pragma unroll
        for (int kf = 0; kf < 8; ++kf) {
            s16x8 a = pack8(*(const f32x4*)(xp + kf * 32),
                            *(const f32x4*)(xp + kf * 32 + 4), 1.0f);
            acc[kf & 1] = MFMA(a, wif[kf], acc[kf & 1]);
        }

        if (s > 0) {
            if (wave == 0) {
                int it = 0;
                for (;;) {
                    int v = rmw_flag<PURE>(inbox + lane, 0);
                    if (__all(v >= s)) break;
                    if (++it > (1 << 14)) break;
                    __builtin_amdgcn_s_sleep(1);
                }
            }
            __syncthreads();

            const char* slice = (const char*)(hbuf + (size_t)((s - 1) & dmask) * BH
                                              + (size_t)b0 * H_SZ);
            long o[16];
#pragma unroll
            for (int r = 0; r < 16; ++r) {
                const long* p = (const long*)(slice + r * 2048) + tid;
                o[r] = PURE ? AGT_LD(p) : SYS_LD(p);
            }
#pragma unroll
            for (int r = 0; r < 16; ++r)
                *(long*)(h_lds + ((r * 2048 + tid * 8) ^ ((r & 7) << 4))) = o[r];
            __syncthreads();

#pragma unroll
            for (int ks = 0; ks < 32; ++ks) {
                s16x8 a = *(const s16x8*)(h_lds + ((rbase + ks * 64) ^ xr));
                acc[ks & 3] = MFMA(a, wh[ks], acc[ks & 3]);
            }
        } else {
#pragma unroll
            for (int ks = 0; ks < 32; ++ks) {
                const float* p = h0 + ks * 32 + lk * 8;
                s16x8 a = pack8(*(const f32x4*)p, *(const f32x4*)(p + 4), KEEP);
                acc[ks & 3] = MFMA(a, wh[ks], acc[ks & 3]);
            }
        }

        f32x4 r4 = (acc[0] + acc[1]) + (acc[2] + acc[3]);

        if (s < S_LEN - 1) {
            short* op = hbuf + (size_t)(s & dmask) * BH;
#pragma unroll
            for (int r = 0; r < 4; ++r)
                sth<PURE>(op + (crow + r) * H_SZ + j, f2bf(KEEP * fast_tanh(r4[r])));
            asm volatile("s_waitcnt vmcnt(0)" ::: "memory");
            if (lane < 16) sig_flag<PURE>(fanout);
        } else {
#pragma unroll
            for (int r = 0; r < 4; ++r)
                out[(crow + r) * H_SZ + j] = fast_tanh(r4[r]);
        }
    }
}

__global__ __launch_bounds__(256, 1) void rnn_coarse(
    const float* __restrict__ x, const float* __restrict__ Wi,
    const float* __restrict__ bias, const float* __restrict__ Wh,
    const float* __restrict__ h0, float* __restrict__ out,
    short* __restrict__ hbuf, int* __restrict__ roster, int* __restrict__ flags,
    int dmask)
{
    __shared__ char h_lds[32768];
    __shared__ int sh_pure;
    const int bid  = blockIdx.x;
    const int role = ((bid & 7) << 5) | (bid >> 3);
    const int g    = role >> 4;
    const int t    = role & 15;
    const int tid  = threadIdx.x;
    const int wave = tid >> 6;
    const int lane = tid & 63;
    const int ln   = lane & 15;
    const int lk   = lane >> 4;

    int xcc;
    asm volatile("s_getreg_b32 %0, hwreg(HW_REG_XCC_ID)" : "=s"(xcc));
    xcc &= 7;
    if (tid == 0) SYS_ST(&roster[role], xcc + 1);
    if (tid < 16) {
        const int* rp = roster + g * 16 + tid;
        int v, it = 0;
        do { v = SYS_LD(rp); if (v) break; if (++it > (1 << 18)) break;
             __builtin_amdgcn_s_sleep(1); } while (1);
        int p = __all(v == __shfl(v, 0));
        if (tid == 0) sh_pure = p;
    }
    __syncthreads();
    const int pure = sh_pure;

    const int b0 = g * 16;
    const int j  = t * 64 + wave * 16 + ln;
    const int wIdx = t * 4 + wave;

    s16x8 wh[32];
#pragma unroll
    for (int ks = 0; ks < 32; ++ks) {
        const float* p = Wh + (size_t)j * H_SZ + ks * 32 + lk * 8;
        wh[ks] = pack8(*(const f32x4*)p, *(const f32x4*)(p + 4), 1.0f);
    }
    s16x8 wif[8];
#pragma unroll
    for (int kf = 0; kf < 8; ++kf) {
        const float* p = Wi + (size_t)j * F_SZ + kf * 32 + lk * 8;
        wif[kf] = pack8(*(const f32x4*)p, *(const f32x4*)(p + 4), 1.0f);
    }
    const float bj = bias[j];

    if (pure)
        step_loop<1>(x, h0, out, hbuf, flags, h_lds, wh, wif, bj,
                     g, b0, role, j, wIdx, wave, lane, tid, dmask);
    else
        step_loop<0>(x, h0, out, hbuf, flags, h_lds, wh, wif, bj,
                     g, b0, role, j, wIdx, wave, lane, tid, dmask);
}

// ---------- kernel A: xi = x@Wi^T + b (sync-free; coalesced output) ----------
// Output layout: [S][role(256)][jt(4)][lane(64)] x 8B. Grid 4096 (2x TLP vs R14).
__global__ __launch_bounds__(256, 1) void xi_gemm(
    const float* __restrict__ x, const float* __restrict__ Wi,
    const float* __restrict__ bias, char* __restrict__ xi)
{
    const int bid  = blockIdx.x;
    const int role = bid & 255;
    const int c    = bid >> 8;          // s-chunk (32 steps), 0..15
    const int tid  = threadIdx.x;
    const int wave = tid >> 6;
    const int lane = tid & 63;
    const int ln   = lane & 15;
    const int lk   = lane >> 4;

    const int b0    = (role >> 4) * 16;
    const int jtile = (role & 15) * 64;

    s16x8 wia[4][8];
    float b4[4];
#pragma unroll
    for (int jt = 0; jt < 4; ++jt) {
        b4[jt] = bias[jtile + jt * 16 + ln];
#pragma unroll
        for (int kf = 0; kf < 8; ++kf) {
            const float* p = Wi + (size_t)(jtile + jt * 16 + ln) * F_SZ
                           + kf * 32 + lk * 8;
            wia[jt][kf] = pack8_pk(*(const f32x4*)p, *(const f32x4*)(p + 4));
        }
    }

#pragma unroll 1
    for (int i = 0; i < 8; ++i) {
        const int s = c * 32 + wave + 4 * i;
        const float* xp = x + ((size_t)s * B_SZ + b0 + ln) * F_SZ + lk * 8;
        s16x8 af[8];
#pragma unroll
        for (int kf = 0; kf < 8; ++kf)
            af[kf] = pack8_pk(*(const f32x4*)(xp + kf * 32),
                              *(const f32x4*)(xp + kf * 32 + 4));
#pragma unroll
        for (int jt = 0; jt < 4; ++jt) {
            f32x4 a = { b4[jt], b4[jt], b4[jt], b4[jt] };
#pragma unroll
            for (int kf = 0; kf < 8; ++kf)
                a = MFMA(af[kf], wia[jt][kf], a);
            // producer lane l holds exactly consumer (role, jt, l)'s 8B
            *(long*)(xi + ((((size_t)s * 256 + role) * 4 + jt) * 64 + lane) * 8)
                = pack4_pk(a);
        }
    }
}

extern "C" void kernel_launch(void* const* d_in, const int* in_sizes, int n_in,
                              void* d_out, int out_size, void* d_ws, size_t ws_size,
                              hipStream_t stream) {
    const float* x  = (const float*)d_in[0];
    const float* Wi = (const float*)d_in[1];
    const float* bi = (const float*)d_in[2];
    const float* Wh = (const float*)d_in[3];
    const float* h0 = (const float*)d_in[4];
    float* out = (float*)d_out;

    int*   roster = (int*)d_ws;                          // <=256 ints @ 0
    int*   flags  = (int*)((char*)d_ws + (4 << 10));     // <=256 inboxes x 64 = 64KB
    short* hbuf   = (short*)((char*)d_ws + (128 << 10)); // depth x 512 KB bf16
    char*  xi     = (char*)d_ws + (128 << 10) + 4 * (size_t)BH * 2;

    const size_t need4   = (128u << 10) + 4 * (size_t)BH * 2;          // ~2.1 MB
    const size_t need_xi = need4 + (size_t)S_LEN * 256 * 4 * 64 * 8;   // ~270.7 MB

    const int dmask = (ws_size >= need4) ? 3 : 1;

    // roster + inboxes MUST be zero every call (graph replays don't re-poison)
    (void)hipMemsetAsync(d_ws, 0, (68 << 10), stream);

    if (ws_size >= need_xi) {
        xi_gemm<<<dim3(4096), dim3(256), 0, stream>>>(x, Wi, bi, xi);
        rnn512<<<dim3(128), dim3(512), 0, stream>>>(
            Wh, h0, out, hbuf, roster, flags, xi, 3);
    } else {
        rnn_coarse<<<dim3(256), dim3(256), 0, stream>>>(
            x, Wi, bi, Wh, h0, out, hbuf, roster, flags, dmask);
    }
}